// Round 4
// baseline (540.398 us; speedup 1.0000x reference)
//
#include <hip/hip_runtime.h>
#include <stdint.h>

// Problem constants (B,S,D_MODEL,N_HEAD) = (4,2048,1024,16), D_K=64
#define Bv 4
#define Sv 2048
#define Dv 1024
#define Hv 16
#define DKv 64
#define BSv (Bv * Sv) // 8192

typedef unsigned short u16;
typedef __attribute__((ext_vector_type(8))) short short8;   // 8 bf16 MFMA A/B frag
typedef __attribute__((ext_vector_type(8))) unsigned short u16x8;
typedef __attribute__((ext_vector_type(4))) unsigned short u16x4;
typedef __attribute__((ext_vector_type(4))) float f32x4;    // 16x16 C/D frag
typedef __attribute__((ext_vector_type(16))) float f32x16;  // 32x32 C/D frag

__device__ __forceinline__ u16 f2bf(float f) {
  union { float f; uint32_t u; } x; x.f = f;
  uint32_t r = x.u + 0x7FFFu + ((x.u >> 16) & 1u);  // round-to-nearest-even
  return (u16)(r >> 16);
}

// async global->LDS, 16B per lane. LDS dest must be wave-uniform base + lane*16.
__device__ __forceinline__ void gl_lds16(const void* g, void* l) {
  __builtin_amdgcn_global_load_lds(
      (__attribute__((address_space(1))) void*)g,
      (__attribute__((address_space(3))) void*)l, 16, 0, 0);
}

__device__ __forceinline__ f32x4 mfma16(short8 a, short8 b, f32x4 c) {
  return __builtin_amdgcn_mfma_f32_16x16x32_bf16(a, b, c, 0, 0, 0);
}
__device__ __forceinline__ f32x16 mfma32(short8 a, short8 b, f32x16 c) {
  return __builtin_amdgcn_mfma_f32_32x32x16_bf16(a, b, c, 0, 0, 0);
}

// counted vmcnt wait (waits THIS wave's outstanding vmem ops down to N)
template <int N>
__device__ __forceinline__ void vwait() {
  asm volatile("s_waitcnt vmcnt(%0)" ::"n"(N) : "memory");
}
// raw workgroup barrier with compiler-level memory fences (no hw drain)
__device__ __forceinline__ void bar() {
  asm volatile("" ::: "memory");
  __builtin_amdgcn_s_barrier();
  asm volatile("" ::: "memory");
}

// ---------------------------------------------------------------------------
// W (fp32, [k][n]) -> W^T (bf16, [n][k]). 64x64 tiles via LDS. z selects weight.
__global__ __launch_bounds__(256) void conv_wt(
    const float* __restrict__ w0, const float* __restrict__ w1,
    const float* __restrict__ w2, const float* __restrict__ w3,
    u16* __restrict__ t0, u16* __restrict__ t1, u16* __restrict__ t2,
    u16* __restrict__ t3) {
  const float* W = (blockIdx.z == 0) ? w0 : (blockIdx.z == 1 ? w1 : (blockIdx.z == 2 ? w2 : w3));
  u16* T = (blockIdx.z == 0) ? t0 : (blockIdx.z == 1 ? t1 : (blockIdx.z == 2 ? t2 : t3));
  __shared__ u16 tile[64][72];  // tile[n][k]
  int nb = blockIdx.x * 64, kb = blockIdx.y * 64;
  int t = threadIdx.x;
#pragma unroll
  for (int p = 0; p < 4; ++p) {
    int idx = p * 256 + t;
    int r = idx >> 4;            // k row within tile
    int c4 = (idx & 15) * 4;     // n col within tile
    float4 vv = *(const float4*)(W + (size_t)(kb + r) * Dv + nb + c4);
    tile[c4 + 0][r] = f2bf(vv.x);
    tile[c4 + 1][r] = f2bf(vv.y);
    tile[c4 + 2][r] = f2bf(vv.z);
    tile[c4 + 3][r] = f2bf(vv.w);
  }
  __syncthreads();
#pragma unroll
  for (int p = 0; p < 4; ++p) {
    int idx = p * 256 + t;
    int r = idx >> 4;            // n row
    int c4 = (idx & 15) * 4;     // k col
    u16x4 o = { tile[r][c4], tile[r][c4 + 1], tile[r][c4 + 2], tile[r][c4 + 3] };
    *(u16x4*)(T + (size_t)(nb + r) * Dv + kb + c4) = o;
  }
}

// ---------------------------------------------------------------------------
// Fused QKV projection GEMM (R4): A is the ORIGINAL fp32 q/k/v (no conv
// kernel, no bf16 round-trip). A-path is reg-staged with PREFETCH DISTANCE 2:
// two register sets fa[2] (parity-indexed); iter t does
//   sync -> stageB(t+1) -> loadA(t+2, set t&1) -> compute(t)
//        -> writeA(tile t+1 from set (t+1)&1 -> LDS buf (t+1)&1)
// so each fa set has ~2 tiles of compute+sync to cover L3/HBM latency before
// its f2bf+ds_write consumes it.  Set ledger: set s holds the tile with
// parity s; at entry of iter t, set t&1's tile (=t) was ds_written at iter
// t-1, so it is dead and refillable with t+2.  writeA targets the LDS buffer
// no wave reads this iter; the next __syncthreads drains lgkm before reads.
// B (weights, bf16, L2-resident) stays on the proven gl_lds path.
// Skeleton = R0's proven 128x128 / 2-buffer / 1-sync structure.
// C[m][n] = sum_k A[m][k]*Bt[n][k], M=8192, N=1024, K=1024.
// mode=z: 0 RoPE*0.125*log2e -> Qp; 1 RoPE -> Kp; 2 transpose -> Vt [bh][64][s]
__global__ __launch_bounds__(256, 2) void gemm_qkv(
    const float* __restrict__ A0, const float* __restrict__ A1, const float* __restrict__ A2,
    const u16* __restrict__ B0, const u16* __restrict__ B1, const u16* __restrict__ B2,
    u16* __restrict__ O0, u16* __restrict__ O1, u16* __restrict__ O2) {
  __shared__ u16 As[2][128 * 64];
  __shared__ u16 Bs[2][128 * 64];
  int z = blockIdx.z;
  const float* A = (z == 0) ? A0 : (z == 1 ? A1 : A2);
  const u16* Bt  = (z == 0) ? B0 : (z == 1 ? B1 : B2);
  u16* Out       = (z == 0) ? O0 : (z == 1 ? O1 : O2);
  int mode = z;

  int tid = threadIdx.x;
  int lane = tid & 63, wid = tid >> 6;
  int quad = lane >> 4, cc = lane & 15;
  int wm = (wid >> 1) * 64, wn = (wid & 1) * 64;
  int m0 = blockIdx.x * 128, n0 = blockIdx.y * 128;

  f32x4 acc[4][4];
#pragma unroll
  for (int mi = 0; mi < 4; ++mi)
#pragma unroll
    for (int ni = 0; ni < 4; ++ni) {
      f32x4 zf = {0.f, 0.f, 0.f, 0.f};
      acc[mi][ni] = zf;
    }

  // B tile staging: 128x64 bf16 via gl_lds (4 slot-groups of 256 threads).
  auto stageB = [&](int ki, int b) {
#pragma unroll
    for (int p = 0; p < 4; ++p) {
      int slot = p * 256 + tid;
      int row = slot >> 3, cl = slot & 7;
      int cg = cl ^ (row & 7);
      gl_lds16(Bt + (size_t)(n0 + row) * Dv + ki * 64 + cg * 8, &Bs[b][slot * 8]);
    }
  };

  // A tile reg-staging: 128x64 fp32 -> 4 chunks/thread of 8 floats, 2 sets.
  float4 fa[2][4][2];
  auto loadA = [&](int ki, int s) {
#pragma unroll
    for (int p = 0; p < 4; ++p) {
      int slot = p * 256 + tid;
      int row = slot >> 3, cl = slot & 7;
      int cg = cl ^ (row & 7);
      const float* g = A + (size_t)(m0 + row) * Dv + ki * 64 + cg * 8;
      fa[s][p][0] = *(const float4*)g;
      fa[s][p][1] = *(const float4*)(g + 4);
    }
  };
  auto writeA = [&](int b, int s) {
#pragma unroll
    for (int p = 0; p < 4; ++p) {
      int slot = p * 256 + tid;
      u16x8 o = { f2bf(fa[s][p][0].x), f2bf(fa[s][p][0].y), f2bf(fa[s][p][0].z), f2bf(fa[s][p][0].w),
                  f2bf(fa[s][p][1].x), f2bf(fa[s][p][1].y), f2bf(fa[s][p][1].z), f2bf(fa[s][p][1].w) };
      *(u16x8*)&As[b][slot * 8] = o;  // ds_write_b128, same swizzled layout
    }
  };

  // prologue: tile0 staged fully; tile1's A in regs (set 1).
  loadA(0, 0); writeA(0, 0); stageB(0, 0);
  loadA(1, 1);

  const int NT = Dv / 64;  // 16
  for (int t = 0; t < NT; ++t) {
    int cur = t & 1;
    __syncthreads();  // drains gl_lds B(t) [vmcnt] + ds_write A(t) [lgkm]

    if (t + 1 < NT) stageB(t + 1, 1 - cur);  // async, nobody reads this tile
    if (t + 2 < NT) loadA(t + 2, cur);       // refill the dead set (parity t)

#pragma unroll
    for (int kk = 0; kk < 2; ++kk) {
      short8 af[4], bfr[4];
#pragma unroll
      for (int mi = 0; mi < 4; ++mi) {
        int row = wm + mi * 16 + cc;
        int cg = kk * 4 + quad;
        af[mi] = *(const short8*)&As[cur][row * 64 + (cg ^ (row & 7)) * 8];
      }
#pragma unroll
      for (int ni = 0; ni < 4; ++ni) {
        int row = wn + ni * 16 + cc;
        int cg = kk * 4 + quad;
        bfr[ni] = *(const short8*)&Bs[cur][row * 64 + (cg ^ (row & 7)) * 8];
      }
#pragma unroll
      for (int mi = 0; mi < 4; ++mi)
#pragma unroll
        for (int ni = 0; ni < 4; ++ni)
          acc[mi][ni] = mfma16(af[mi], bfr[ni], acc[mi][ni]);
    }

    if (t + 1 < NT) writeA(1 - cur, 1 - cur);  // cvt+ds_write tile t+1 (set (t+1)&1)
  }

  // Epilogue. C/D layout: col n = lane&15, row m = quad*4 + reg.
  if (mode <= 1) {
    float postscale = (mode == 0) ? 0.18033688011112042f : 1.0f; // 1/8*log2e
#pragma unroll
    for (int ni = 0; ni < 4; ++ni) {
      int n = n0 + wn + ni * 16 + cc;
      int h = n >> 6, d = n & 63;
      float inv = __expf(-(float)(d & 62) * (9.210340372f / 64.0f)); // theta^{-2i/64}
      float sign = (d & 1) ? 1.0f : -1.0f;
#pragma unroll
      for (int mi = 0; mi < 4; ++mi) {
        int mB = m0 + wm + mi * 16 + quad * 4;
#pragma unroll
        for (int r = 0; r < 4; ++r) {
          int m = mB + r;
          int b = m >> 11, s = m & (Sv - 1);
          float val = acc[mi][ni][r];
          float part = __shfl_xor(val, 1);  // paired even/odd feature
          float sn, cs;
          __sincosf((float)s * inv, &sn, &cs);
          float outv = (val * cs + sign * part * sn) * postscale;
          Out[((size_t)(b * Hv + h) * Sv + s) * DKv + d] = f2bf(outv);
        }
      }
    }
  } else {
#pragma unroll
    for (int ni = 0; ni < 4; ++ni) {
      int n = n0 + wn + ni * 16 + cc;
      int h = n >> 6, d = n & 63;
#pragma unroll
      for (int mi = 0; mi < 4; ++mi) {
        int mB = m0 + wm + mi * 16 + quad * 4;
        int b = mB >> 11, s = mB & (Sv - 1);
        u16x4 o4 = { f2bf(acc[mi][ni][0]), f2bf(acc[mi][ni][1]),
                     f2bf(acc[mi][ni][2]), f2bf(acc[mi][ni][3]) };
        *(u16x4*)&Out[((size_t)(b * Hv + h) * DKv + d) * Sv + s] = o4;
      }
    }
  }
}

// ---------------------------------------------------------------------------
// Out-projection GEMM (bf16 ctx x Wot -> fp32 out). R2 kernel kept verbatim,
// called with modeSel=3 only. BM=256, BN=128, BK=64, 512 thr, 3-buffer LDS,
// phase-interleaved counted-vmcnt schedule (safety ledger in R2 notes).
__global__ __launch_bounds__(512, 2) void gemm_bt(
    const u16* __restrict__ A0, const u16* __restrict__ A1, const u16* __restrict__ A2,
    const u16* __restrict__ B0, const u16* __restrict__ B1, const u16* __restrict__ B2,
    void* __restrict__ O0, void* __restrict__ O1, void* __restrict__ O2,
    int modeSel) {
  __shared__ u16 As[3][256 * 64];   // 96 KB
  __shared__ u16 Bs[3][128 * 64];   // 48 KB
  int z = blockIdx.z;
  const u16* A  = (z == 0) ? A0 : (z == 1 ? A1 : A2);
  const u16* Bt = (z == 0) ? B0 : (z == 1 ? B1 : B2);
  void* Out     = (z == 0) ? O0 : (z == 1 ? O1 : O2);
  int mode = (modeSel < 0) ? z : modeSel;

  int tid = threadIdx.x;
  int lane = tid & 63, wid = tid >> 6;
  int quad = lane >> 4, cc = lane & 15;
  int wm = (wid >> 1) * 64, wn = (wid & 1) * 64;   // 4M x 2N waves of 64x64
  int bx = blockIdx.x;
  int swz = (bx & 7) * 32 + (bx >> 3);             // XCD chunk swizzle (256 blocks)
  int m0 = (swz >> 3) * 256, n0 = (swz & 7) * 128;

  f32x4 acc[4][4];
#pragma unroll
  for (int mi = 0; mi < 4; ++mi)
#pragma unroll
    for (int ni = 0; ni < 4; ++ni) {
      f32x4 zf = {0.f, 0.f, 0.f, 0.f};
      acc[mi][ni] = zf;
    }

  auto stageA2 = [&](int ki, int b, int p0) {
#pragma unroll
    for (int p = 0; p < 2; ++p) {
      int slot = (p0 + p) * 512 + tid;
      int row = slot >> 3, cl = slot & 7;
      int cg = cl ^ (row & 7);
      gl_lds16(A + (size_t)(m0 + row) * Dv + ki * 64 + cg * 8, &As[b][slot * 8]);
    }
  };
  auto stageB1 = [&](int ki, int b, int p0) {
    int slot = p0 * 512 + tid;
    int row = slot >> 3, cl = slot & 7;
    int cg = cl ^ (row & 7);
    gl_lds16(Bt + (size_t)(n0 + row) * Dv + ki * 64 + cg * 8, &Bs[b][slot * 8]);
  };

  // prologue: tile0 -> buf0 (6 loads), tile1 -> buf1 (6 loads), in order.
  stageA2(0, 0, 0); stageA2(0, 0, 2); stageB1(0, 0, 0); stageB1(0, 0, 1);
  stageA2(1, 1, 0); stageA2(1, 1, 2); stageB1(1, 1, 0); stageB1(1, 1, 1);
  vwait<6>();   // retire tile0's 6; tile1's may stay in flight
  bar();

  const int NT = Dv / 64;  // 16
  int cur = 0, nxt = 2;
#pragma unroll 1
  for (int t = 0; t < NT; ++t) {
    const u16* Ac = &As[cur][0];
    const u16* Bc = &Bs[cur][0];
#pragma unroll
    for (int kk = 0; kk < 2; ++kk) {
      short8 af[4], bfr[4];
#pragma unroll
      for (int mi = 0; mi < 4; ++mi) {
        int row = wm + mi * 16 + cc;
        int cg = kk * 4 + quad;
        af[mi] = *(const short8*)&Ac[row * 64 + (cg ^ (row & 7)) * 8];
      }
#pragma unroll
      for (int ni = 0; ni < 4; ++ni) {
        int row = wn + ni * 16 + cc;
        int cg = kk * 4 + quad;
        bfr[ni] = *(const short8*)&Bc[row * 64 + (cg ^ (row & 7)) * 8];
      }
      if (t + 2 < NT) {       // half of tile t+2's staging per phase
        if (kk == 0) { stageA2(t + 2, nxt, 0); stageB1(t + 2, nxt, 0); }
        else         { stageA2(t + 2, nxt, 2); stageB1(t + 2, nxt, 1); }
      }
      bar();                  // phase lockstep; compiler lgkmcnt covers ds deps
      __builtin_amdgcn_s_setprio(1);
#pragma unroll
      for (int mi = 0; mi < 4; ++mi)
#pragma unroll
        for (int ni = 0; ni < 4; ++ni)
          acc[mi][ni] = mfma16(af[mi], bfr[ni], acc[mi][ni]);
      __builtin_amdgcn_s_setprio(0);
      if (kk == 0) bar();
    }
    if (t < NT - 1) {         // tile boundary: make buf[(t+1)%3] readable
      if (t + 2 < NT) vwait<6>(); else vwait<0>();
      bar();
    }
    cur = (cur == 2) ? 0 : cur + 1;
    nxt = (nxt == 2) ? 0 : nxt + 1;
  }

  // Epilogue. C/D layout: col n = lane&15, row m = quad*4 + reg.
  if (mode <= 1) {
    u16* O = (u16*)Out;
    float postscale = (mode == 0) ? 0.18033688011112042f : 1.0f; // 1/8*log2e
#pragma unroll
    for (int ni = 0; ni < 4; ++ni) {
      int n = n0 + wn + ni * 16 + cc;
      int h = n >> 6, d = n & 63;
      float inv = __expf(-(float)(d & 62) * (9.210340372f / 64.0f)); // theta^{-2i/64}
      float sign = (d & 1) ? 1.0f : -1.0f;
#pragma unroll
      for (int mi = 0; mi < 4; ++mi) {
        int mB = m0 + wm + mi * 16 + quad * 4;
#pragma unroll
        for (int r = 0; r < 4; ++r) {
          int m = mB + r;
          int b = m >> 11, s = m & (Sv - 1);
          float val = acc[mi][ni][r];
          float part = __shfl_xor(val, 1);  // paired even/odd feature
          float sn, cs;
          __sincosf((float)s * inv, &sn, &cs);
          float outv = (val * cs + sign * part * sn) * postscale;
          O[((size_t)(b * Hv + h) * Sv + s) * DKv + d] = f2bf(outv);
        }
      }
    }
  } else if (mode == 2) {
    u16* O = (u16*)Out;
#pragma unroll
    for (int ni = 0; ni < 4; ++ni) {
      int n = n0 + wn + ni * 16 + cc;
      int h = n >> 6, d = n & 63;
#pragma unroll
      for (int mi = 0; mi < 4; ++mi) {
        int mB = m0 + wm + mi * 16 + quad * 4;
        int b = mB >> 11, s = mB & (Sv - 1);
        u16x4 o4 = { f2bf(acc[mi][ni][0]), f2bf(acc[mi][ni][1]),
                     f2bf(acc[mi][ni][2]), f2bf(acc[mi][ni][3]) };
        *(u16x4*)&O[((size_t)(b * Hv + h) * DKv + d) * Sv + s] = o4;
      }
    }
  } else {
    float* O = (float*)Out;
#pragma unroll
    for (int ni = 0; ni < 4; ++ni) {
      int n = n0 + wn + ni * 16 + cc;
#pragma unroll
      for (int mi = 0; mi < 4; ++mi) {
        int mB = m0 + wm + mi * 16 + quad * 4;
#pragma unroll
        for (int r = 0; r < 4; ++r)
          O[(size_t)(mB + r) * Dv + n] = acc[mi][ni][r];
      }
    }
  }
}

// ---------------------------------------------------------------------------
// Flash attention v6 (proven 91 us) — reverted verbatim from R2.
// S^T via A=K,B=Q (C col=q=c32); l via ones-B MFMA on the exchanged pu frag;
// K/V double-buffered, 33 KB LDS, __launch_bounds__(256,2).
// Qp,Kp: [bh][s][64] bf16 (Q pre-scaled by 0.125*log2e). Vt: [bh][64][s] bf16.
__global__ __launch_bounds__(256, 2) void attn(
    const u16* __restrict__ Qp, const u16* __restrict__ Kp,
    const u16* __restrict__ Vt, u16* __restrict__ ctx) {
  __shared__ u16 Ks[2][64 * 64];   // [buf][key][d], chunk-swizzled
  __shared__ u16 Vs[2][64 * 64];   // [buf][d][key], chunk-swizzled
  int tid = threadIdx.x;
  int lane = tid & 63, wid = tid >> 6;
  int hi = lane >> 5, c32 = lane & 31;
  int sz = (c32 & 7) ^ ((c32 >> 3) & 3);
  int bh = blockIdx.y;
  int q0 = blockIdx.x * 256 + wid * 64;
  const u16* Qh = Qp + (size_t)bh * Sv * DKv;
  const u16* Kh = Kp + (size_t)bh * Sv * DKv;
  const u16* Vh = Vt + (size_t)bh * Sv * DKv;

  const short8 ones = { (short)0x3F80, (short)0x3F80, (short)0x3F80, (short)0x3F80,
                        (short)0x3F80, (short)0x3F80, (short)0x3F80, (short)0x3F80 };

  // Q B-frags in registers: B[n=q=c32][k = dk*16 + hi*8 + j]
  short8 qf[2][4];
#pragma unroll
  for (int qs = 0; qs < 2; ++qs)
#pragma unroll
    for (int dk = 0; dk < 4; ++dk)
      qf[qs][dk] = *(const short8*)&Qh[(size_t)(q0 + qs * 32 + c32) * DKv + dk * 16 + hi * 8];

  f32x16 o[2][2];   // O[q][d] accum, C-layout: col=d=c32, row=q=(r&3)+8*(r>>2)+4*hi
  f32x16 ol[2];     // l accum (ones-MFMA row sums of bf16 P) — reg r matches o reg r
#pragma unroll
  for (int qs = 0; qs < 2; ++qs) {
#pragma unroll
    for (int dt = 0; dt < 2; ++dt)
#pragma unroll
      for (int r = 0; r < 16; ++r) o[qs][dt][r] = 0.f;
#pragma unroll
    for (int r = 0; r < 16; ++r) ol[qs][r] = 0.f;
  }

  // prefetch tile 0 into buf 0
#pragma unroll
  for (int p = 0; p < 2; ++p) {
    int slot = p * 256 + tid;
    int row = slot >> 3, cl = slot & 7;
    int cg = cl ^ ((row & 7) ^ ((row >> 3) & 3));
    gl_lds16(Kh + (size_t)row * DKv + cg * 8, &Ks[0][slot * 8]);
    gl_lds16(Vh + (size_t)row * Sv + cg * 8, &Vs[0][slot * 8]);
  }

  for (int kt = 0; kt < Sv / 64; ++kt) {
    int cur = kt & 1;
    __syncthreads();  // drains prefetch(kt); all waves past compute(kt-1)

    if (kt + 1 < Sv / 64) {
      int s1 = (kt + 1) * 64;
#pragma unroll
      for (int p = 0; p < 2; ++p) {
        int slot = p * 256 + tid;
        int row = slot >> 3, cl = slot & 7;
        int cg = cl ^ ((row & 7) ^ ((row >> 3) & 3));
        gl_lds16(Kh + (size_t)(s1 + row) * DKv + cg * 8, &Ks[1 - cur][slot * 8]);
        gl_lds16(Vh + (size_t)row * Sv + s1 + cg * 8, &Vs[1 - cur][slot * 8]);
      }
    }

#pragma unroll
    for (int half = 0; half < 2; ++half) {   // 32-key half = key-tile rows
      // K A-frags once per half, shared by both q-halves.
      short8 kf[4];
#pragma unroll
      for (int dk = 0; dk < 4; ++dk)
        kf[dk] = *(const short8*)&Ks[cur][(half * 32 + c32) * 64 + (((dk * 2 + hi) ^ sz)) * 8];

      // S^T for both q-halves: A=K rows (half*32+c32), B=Q. C col = q = c32.
      f32x16 st[2];
#pragma unroll
      for (int qs = 0; qs < 2; ++qs) {
#pragma unroll
        for (int r = 0; r < 16; ++r) st[qs][r] = 0.f;
#pragma unroll
        for (int dk = 0; dk < 4; ++dk)
          st[qs] = mfma32(kf[dk], qf[qs][dk], st[qs]);
      }

      // Two PV k-steps (16 keys each); vf loaded once, shared by both qs.
#pragma unroll
      for (int pp = 0; pp < 2; ++pp) {
        int pk = half * 2 + pp;
        short8 vf[2];
#pragma unroll
        for (int dt = 0; dt < 2; ++dt)
          vf[dt] = *(const short8*)&Vs[cur][(dt * 32 + c32) * 64 + (((pk * 2 + hi) ^ sz)) * 8];
#pragma unroll
        for (int qs = 0; qs < 2; ++qs) {
          float e0 = __builtin_amdgcn_exp2f(st[qs][8 * pp + 0]);
          float e1 = __builtin_amdgcn_exp2f(st[qs][8 * pp + 1]);
          float e2 = __builtin_amdgcn_exp2f(st[qs][8 * pp + 2]);
          float e3 = __builtin_amdgcn_exp2f(st[qs][8 * pp + 3]);
          float e4 = __builtin_amdgcn_exp2f(st[qs][8 * pp + 4]);
          float e5 = __builtin_amdgcn_exp2f(st[qs][8 * pp + 5]);
          float e6 = __builtin_amdgcn_exp2f(st[qs][8 * pp + 6]);
          float e7 = __builtin_amdgcn_exp2f(st[qs][8 * pp + 7]);
          uint32_t plo0 = __builtin_amdgcn_perm(__float_as_uint(e1), __float_as_uint(e0), 0x07060302u);
          uint32_t plo1 = __builtin_amdgcn_perm(__float_as_uint(e3), __float_as_uint(e2), 0x07060302u);
          uint32_t phi0 = __builtin_amdgcn_perm(__float_as_uint(e5), __float_as_uint(e4), 0x07060302u);
          uint32_t phi1 = __builtin_amdgcn_perm(__float_as_uint(e7), __float_as_uint(e6), 0x07060302u);
          uint32_t s0 = hi ? plo0 : phi0;   // pack pair sent to partner lane
          uint32_t s1 = hi ? plo1 : phi1;
          uint32_t r0 = (uint32_t)__shfl_xor((int)s0, 32);
          uint32_t r1 = (uint32_t)__shfl_xor((int)s1, 32);
          union { uint32_t u[4]; short8 s8; } pu;
          pu.u[0] = hi ? r0 : plo0;   // frag elems 0..3: data from h'=0 lane
          pu.u[1] = hi ? r1 : plo1;
          pu.u[2] = hi ? phi0 : r0;   // frag elems 4..7: data from h'=1 lane
          pu.u[3] = hi ? phi1 : r1;
          ol[qs] = mfma32(pu.s8, ones, ol[qs]);
          o[qs][0] = mfma32(pu.s8, vf[0], o[qs][0]);
          o[qs][1] = mfma32(pu.s8, vf[1], o[qs][1]);
        }
      }
    }
  }

  // normalize + write ctx[b][s=q][h*64+d]. ol reg r is the l of o reg r's row.
  int b = bh >> 4, h = bh & 15;
#pragma unroll
  for (int qs = 0; qs < 2; ++qs)
#pragma unroll
    for (int r = 0; r < 16; ++r) {
      int q = q0 + qs * 32 + (r & 3) + 8 * (r >> 2) + 4 * hi;
      float linv = 1.0f / ol[qs][r];
#pragma unroll
      for (int dt = 0; dt < 2; ++dt) {
        int d = h * DKv + dt * 32 + c32;
        ctx[((size_t)b * Sv + q) * Dv + d] = f2bf(o[qs][dt][r] * linv);
      }
    }
}

// ---------------------------------------------------------------------------
extern "C" void kernel_launch(void* const* d_in, const int* in_sizes, int n_in,
                              void* d_out, int out_size, void* d_ws, size_t ws_size,
                              hipStream_t stream) {
  (void)in_sizes; (void)n_in; (void)out_size; (void)ws_size;
  const float* q  = (const float*)d_in[0];
  const float* k  = (const float*)d_in[1];
  const float* v  = (const float*)d_in[2];
  const float* Wq = (const float*)d_in[3];
  const float* Wk = (const float*)d_in[4];
  const float* Wv = (const float*)d_in[5];
  const float* Wo = (const float*)d_in[6];

  char* ws = (char*)d_ws;
  size_t off = 0;
  const size_t big = (size_t)BSv * Dv * sizeof(u16);   // 16 MiB
  const size_t wsz = (size_t)Dv * Dv * sizeof(u16);    // 2 MiB
  u16* Wqt = (u16*)(ws + off); off += wsz;
  u16* Wkt = (u16*)(ws + off); off += wsz;
  u16* Wvt = (u16*)(ws + off); off += wsz;
  u16* Wot = (u16*)(ws + off); off += wsz;
  u16* Qp  = (u16*)(ws + off); off += big;
  u16* Kp  = (u16*)(ws + off); off += big;
  u16* Vtr = (u16*)(ws + off); off += big;
  u16* ctx = (u16*)(ws + off); off += big;

  conv_wt<<<dim3(Dv / 64, Dv / 64, 4), 256, 0, stream>>>(Wq, Wk, Wv, Wo, Wqt, Wkt, Wvt, Wot);
  // fused conv+projection: reads fp32 q/k/v directly, mode = z
  gemm_qkv<<<dim3(BSv / 128, Dv / 128, 3), 256, 0, stream>>>(
      q, k, v, Wqt, Wkt, Wvt, Qp, Kp, Vtr);
  attn<<<dim3(Sv / 256, Bv * Hv), 256, 0, stream>>>(Qp, Kp, Vtr, ctx);
  gemm_bt<<<dim3(256, 1, 1), 512, 0, stream>>>(
      ctx, ctx, ctx, Wot, Wot, Wot, d_out, d_out, d_out, 3);
}

// Round 5
// 322.234 us; speedup vs baseline: 1.6770x; 1.6770x over previous
//
#include <hip/hip_runtime.h>
#include <stdint.h>

// Problem constants (B,S,D_MODEL,N_HEAD) = (4,2048,1024,16), D_K=64
#define Bv 4
#define Sv 2048
#define Dv 1024
#define Hv 16
#define DKv 64
#define BSv (Bv * Sv) // 8192

typedef unsigned short u16;
typedef __attribute__((ext_vector_type(8))) short short8;   // 8 bf16 MFMA A/B frag
typedef __attribute__((ext_vector_type(8))) unsigned short u16x8;
typedef __attribute__((ext_vector_type(4))) unsigned short u16x4;
typedef __attribute__((ext_vector_type(4))) float f32x4;    // 16x16 C/D frag
typedef __attribute__((ext_vector_type(16))) float f32x16;  // 32x32 C/D frag

__device__ __forceinline__ u16 f2bf(float f) {
  union { float f; uint32_t u; } x; x.f = f;
  uint32_t r = x.u + 0x7FFFu + ((x.u >> 16) & 1u);  // round-to-nearest-even
  return (u16)(r >> 16);
}

// async global->LDS, 16B per lane. LDS dest must be wave-uniform base + lane*16.
__device__ __forceinline__ void gl_lds16(const void* g, void* l) {
  __builtin_amdgcn_global_load_lds(
      (__attribute__((address_space(1))) void*)g,
      (__attribute__((address_space(3))) void*)l, 16, 0, 0);
}

__device__ __forceinline__ f32x4 mfma16(short8 a, short8 b, f32x4 c) {
  return __builtin_amdgcn_mfma_f32_16x16x32_bf16(a, b, c, 0, 0, 0);
}
__device__ __forceinline__ f32x16 mfma32(short8 a, short8 b, f32x16 c) {
  return __builtin_amdgcn_mfma_f32_32x32x16_bf16(a, b, c, 0, 0, 0);
}

// counted vmcnt wait (waits THIS wave's outstanding vmem ops down to N)
template <int N>
__device__ __forceinline__ void vwait() {
  asm volatile("s_waitcnt vmcnt(%0)" ::"n"(N) : "memory");
}
// raw workgroup barrier with compiler-level memory fences (no hw drain)
__device__ __forceinline__ void bar() {
  asm volatile("" ::: "memory");
  __builtin_amdgcn_s_barrier();
  asm volatile("" ::: "memory");
}

// ---------------------------------------------------------------------------
// W (fp32, [k][n]) -> W^T (bf16, [n][k]). 64x64 tiles via LDS. z selects weight.
__global__ __launch_bounds__(256) void conv_wt(
    const float* __restrict__ w0, const float* __restrict__ w1,
    const float* __restrict__ w2, const float* __restrict__ w3,
    u16* __restrict__ t0, u16* __restrict__ t1, u16* __restrict__ t2,
    u16* __restrict__ t3) {
  const float* W = (blockIdx.z == 0) ? w0 : (blockIdx.z == 1 ? w1 : (blockIdx.z == 2 ? w2 : w3));
  u16* T = (blockIdx.z == 0) ? t0 : (blockIdx.z == 1 ? t1 : (blockIdx.z == 2 ? t2 : t3));
  __shared__ u16 tile[64][72];  // tile[n][k]
  int nb = blockIdx.x * 64, kb = blockIdx.y * 64;
  int t = threadIdx.x;
#pragma unroll
  for (int p = 0; p < 4; ++p) {
    int idx = p * 256 + t;
    int r = idx >> 4;            // k row within tile
    int c4 = (idx & 15) * 4;     // n col within tile
    float4 vv = *(const float4*)(W + (size_t)(kb + r) * Dv + nb + c4);
    tile[c4 + 0][r] = f2bf(vv.x);
    tile[c4 + 1][r] = f2bf(vv.y);
    tile[c4 + 2][r] = f2bf(vv.z);
    tile[c4 + 3][r] = f2bf(vv.w);
  }
  __syncthreads();
#pragma unroll
  for (int p = 0; p < 4; ++p) {
    int idx = p * 256 + t;
    int r = idx >> 4;            // n row
    int c4 = (idx & 15) * 4;     // k col
    u16x4 o = { tile[r][c4], tile[r][c4 + 1], tile[r][c4 + 2], tile[r][c4 + 3] };
    *(u16x4*)(T + (size_t)(nb + r) * Dv + kb + c4) = o;
  }
}

// ---------------------------------------------------------------------------
// Fused QKV projection GEMM (R5): R4's distance-2 A-pipeline with the rule#20
// fix — the two A register sets are NAMED locals (fa0, fa1) and the K-loop is
// unrolled x2 so every register-array index is compile-time. R4's runtime
// fa[cur] indexing sent the array to scratch (813 MB spill writes, 334 us).
// Schedule per unrolled pair (t=tt even, t+1 odd):
//   even: sync; stageB(t+1->buf1); loadA(t+2->fa0); compute(buf0); writeA(fa1->As[1])
//   odd : sync; stageB(t+2->buf0); loadA(t+3->fa1); compute(buf1); writeA(fa0->As[0])
// Set ledger: fa0 holds even tiles, fa1 odd tiles. At even-iter entry fa0's
// tile t was ds_written at iter t-1 -> dead, refill with t+2 (and vice versa).
// Each set has ~2 compute phases + syncs to cover L3/HBM latency before its
// f2bf+ds_write consumes it. writeA targets the LDS buffer no wave reads this
// iter; the next __syncthreads drains lgkm before reads. Guards uniform in t.
// B (weights, bf16, L2-resident) stays on the proven gl_lds path.
// C[m][n] = sum_k A[m][k]*Bt[n][k], M=8192, N=1024, K=1024.
// mode=z: 0 RoPE*0.125*log2e -> Qp; 1 RoPE -> Kp; 2 transpose -> Vt [bh][64][s]
__global__ __launch_bounds__(256, 2) void gemm_qkv(
    const float* __restrict__ A0, const float* __restrict__ A1, const float* __restrict__ A2,
    const u16* __restrict__ B0, const u16* __restrict__ B1, const u16* __restrict__ B2,
    u16* __restrict__ O0, u16* __restrict__ O1, u16* __restrict__ O2) {
  __shared__ u16 As[2][128 * 64];
  __shared__ u16 Bs[2][128 * 64];
  int z = blockIdx.z;
  const float* A = (z == 0) ? A0 : (z == 1 ? A1 : A2);
  const u16* Bt  = (z == 0) ? B0 : (z == 1 ? B1 : B2);
  u16* Out       = (z == 0) ? O0 : (z == 1 ? O1 : O2);
  int mode = z;

  int tid = threadIdx.x;
  int lane = tid & 63, wid = tid >> 6;
  int quad = lane >> 4, cc = lane & 15;
  int wm = (wid >> 1) * 64, wn = (wid & 1) * 64;
  int m0 = blockIdx.x * 128, n0 = blockIdx.y * 128;

  f32x4 acc[4][4];
#pragma unroll
  for (int mi = 0; mi < 4; ++mi)
#pragma unroll
    for (int ni = 0; ni < 4; ++ni) {
      f32x4 zf = {0.f, 0.f, 0.f, 0.f};
      acc[mi][ni] = zf;
    }

  // B tile staging: 128x64 bf16 via gl_lds (4 slot-groups of 256 threads).
  auto stageB = [&](int ki, int b) {
#pragma unroll
    for (int p = 0; p < 4; ++p) {
      int slot = p * 256 + tid;
      int row = slot >> 3, cl = slot & 7;
      int cg = cl ^ (row & 7);
      gl_lds16(Bt + (size_t)(n0 + row) * Dv + ki * 64 + cg * 8, &Bs[b][slot * 8]);
    }
  };

  // A tile reg-staging: 128x64 fp32 -> 4 chunks/thread of 8 floats.
  // TWO NAMED sets; all indices into them are compile-time (rule #20).
  float4 fa0[4][2], fa1[4][2];
  auto loadA = [&](int ki, float4 (&fs)[4][2]) {
#pragma unroll
    for (int p = 0; p < 4; ++p) {
      int slot = p * 256 + tid;
      int row = slot >> 3, cl = slot & 7;
      int cg = cl ^ (row & 7);
      const float* g = A + (size_t)(m0 + row) * Dv + ki * 64 + cg * 8;
      fs[p][0] = *(const float4*)g;
      fs[p][1] = *(const float4*)(g + 4);
    }
  };
  auto writeA = [&](int b, const float4 (&fs)[4][2]) {
#pragma unroll
    for (int p = 0; p < 4; ++p) {
      int slot = p * 256 + tid;
      u16x8 o = { f2bf(fs[p][0].x), f2bf(fs[p][0].y), f2bf(fs[p][0].z), f2bf(fs[p][0].w),
                  f2bf(fs[p][1].x), f2bf(fs[p][1].y), f2bf(fs[p][1].z), f2bf(fs[p][1].w) };
      *(u16x8*)&As[b][slot * 8] = o;  // ds_write_b128, same swizzled layout
    }
  };
  auto computeTile = [&](int cur) {
#pragma unroll
    for (int kk = 0; kk < 2; ++kk) {
      short8 af[4], bfr[4];
#pragma unroll
      for (int mi = 0; mi < 4; ++mi) {
        int row = wm + mi * 16 + cc;
        int cg = kk * 4 + quad;
        af[mi] = *(const short8*)&As[cur][row * 64 + (cg ^ (row & 7)) * 8];
      }
#pragma unroll
      for (int ni = 0; ni < 4; ++ni) {
        int row = wn + ni * 16 + cc;
        int cg = kk * 4 + quad;
        bfr[ni] = *(const short8*)&Bs[cur][row * 64 + (cg ^ (row & 7)) * 8];
      }
#pragma unroll
      for (int mi = 0; mi < 4; ++mi)
#pragma unroll
        for (int ni = 0; ni < 4; ++ni)
          acc[mi][ni] = mfma16(af[mi], bfr[ni], acc[mi][ni]);
    }
  };

  // prologue: tile0 fully staged; tile1's A in regs (fa1).
  loadA(0, fa0); writeA(0, fa0); stageB(0, 0);
  loadA(1, fa1);

  const int NT = Dv / 64;  // 16 (even)
#pragma unroll 1
  for (int tt = 0; tt < NT; tt += 2) {
    // ---- even phase: t = tt, cur = 0 ----
    __syncthreads();  // drains gl_lds B(tt) [vmcnt] + ds_write A(tt) [lgkm]
    if (tt + 1 < NT) stageB(tt + 1, 1);
    if (tt + 2 < NT) loadA(tt + 2, fa0);   // fa0 dead (tile tt ds_written @ tt-1)
    computeTile(0);
    if (tt + 1 < NT) writeA(1, fa1);       // tile tt+1 -> As[1]
    // ---- odd phase: t = tt+1, cur = 1 ----
    __syncthreads();
    if (tt + 2 < NT) stageB(tt + 2, 0);
    if (tt + 3 < NT) loadA(tt + 3, fa1);   // fa1 dead (tile tt+1 just written)
    computeTile(1);
    if (tt + 2 < NT) writeA(0, fa0);       // tile tt+2 -> As[0]
  }

  // Epilogue. C/D layout: col n = lane&15, row m = quad*4 + reg.
  if (mode <= 1) {
    float postscale = (mode == 0) ? 0.18033688011112042f : 1.0f; // 1/8*log2e
#pragma unroll
    for (int ni = 0; ni < 4; ++ni) {
      int n = n0 + wn + ni * 16 + cc;
      int h = n >> 6, d = n & 63;
      float inv = __expf(-(float)(d & 62) * (9.210340372f / 64.0f)); // theta^{-2i/64}
      float sign = (d & 1) ? 1.0f : -1.0f;
#pragma unroll
      for (int mi = 0; mi < 4; ++mi) {
        int mB = m0 + wm + mi * 16 + quad * 4;
#pragma unroll
        for (int r = 0; r < 4; ++r) {
          int m = mB + r;
          int b = m >> 11, s = m & (Sv - 1);
          float val = acc[mi][ni][r];
          float part = __shfl_xor(val, 1);  // paired even/odd feature
          float sn, cs;
          __sincosf((float)s * inv, &sn, &cs);
          float outv = (val * cs + sign * part * sn) * postscale;
          Out[((size_t)(b * Hv + h) * Sv + s) * DKv + d] = f2bf(outv);
        }
      }
    }
  } else {
#pragma unroll
    for (int ni = 0; ni < 4; ++ni) {
      int n = n0 + wn + ni * 16 + cc;
      int h = n >> 6, d = n & 63;
#pragma unroll
      for (int mi = 0; mi < 4; ++mi) {
        int mB = m0 + wm + mi * 16 + quad * 4;
        int b = mB >> 11, s = mB & (Sv - 1);
        u16x4 o4 = { f2bf(acc[mi][ni][0]), f2bf(acc[mi][ni][1]),
                     f2bf(acc[mi][ni][2]), f2bf(acc[mi][ni][3]) };
        *(u16x4*)&Out[((size_t)(b * Hv + h) * DKv + d) * Sv + s] = o4;
      }
    }
  }
}

// ---------------------------------------------------------------------------
// Out-projection GEMM (bf16 ctx x Wot -> fp32 out). R2 kernel kept verbatim,
// called with modeSel=3 only. BM=256, BN=128, BK=64, 512 thr, 3-buffer LDS,
// phase-interleaved counted-vmcnt schedule (safety ledger in R2 notes).
__global__ __launch_bounds__(512, 2) void gemm_bt(
    const u16* __restrict__ A0, const u16* __restrict__ A1, const u16* __restrict__ A2,
    const u16* __restrict__ B0, const u16* __restrict__ B1, const u16* __restrict__ B2,
    void* __restrict__ O0, void* __restrict__ O1, void* __restrict__ O2,
    int modeSel) {
  __shared__ u16 As[3][256 * 64];   // 96 KB
  __shared__ u16 Bs[3][128 * 64];   // 48 KB
  int z = blockIdx.z;
  const u16* A  = (z == 0) ? A0 : (z == 1 ? A1 : A2);
  const u16* Bt = (z == 0) ? B0 : (z == 1 ? B1 : B2);
  void* Out     = (z == 0) ? O0 : (z == 1 ? O1 : O2);
  int mode = (modeSel < 0) ? z : modeSel;

  int tid = threadIdx.x;
  int lane = tid & 63, wid = tid >> 6;
  int quad = lane >> 4, cc = lane & 15;
  int wm = (wid >> 1) * 64, wn = (wid & 1) * 64;   // 4M x 2N waves of 64x64
  int bx = blockIdx.x;
  int swz = (bx & 7) * 32 + (bx >> 3);             // XCD chunk swizzle (256 blocks)
  int m0 = (swz >> 3) * 256, n0 = (swz & 7) * 128;

  f32x4 acc[4][4];
#pragma unroll
  for (int mi = 0; mi < 4; ++mi)
#pragma unroll
    for (int ni = 0; ni < 4; ++ni) {
      f32x4 zf = {0.f, 0.f, 0.f, 0.f};
      acc[mi][ni] = zf;
    }

  auto stageA2 = [&](int ki, int b, int p0) {
#pragma unroll
    for (int p = 0; p < 2; ++p) {
      int slot = (p0 + p) * 512 + tid;
      int row = slot >> 3, cl = slot & 7;
      int cg = cl ^ (row & 7);
      gl_lds16(A + (size_t)(m0 + row) * Dv + ki * 64 + cg * 8, &As[b][slot * 8]);
    }
  };
  auto stageB1 = [&](int ki, int b, int p0) {
    int slot = p0 * 512 + tid;
    int row = slot >> 3, cl = slot & 7;
    int cg = cl ^ (row & 7);
    gl_lds16(Bt + (size_t)(n0 + row) * Dv + ki * 64 + cg * 8, &Bs[b][slot * 8]);
  };

  // prologue: tile0 -> buf0 (6 loads), tile1 -> buf1 (6 loads), in order.
  stageA2(0, 0, 0); stageA2(0, 0, 2); stageB1(0, 0, 0); stageB1(0, 0, 1);
  stageA2(1, 1, 0); stageA2(1, 1, 2); stageB1(1, 1, 0); stageB1(1, 1, 1);
  vwait<6>();   // retire tile0's 6; tile1's may stay in flight
  bar();

  const int NT = Dv / 64;  // 16
  int cur = 0, nxt = 2;
#pragma unroll 1
  for (int t = 0; t < NT; ++t) {
    const u16* Ac = &As[cur][0];
    const u16* Bc = &Bs[cur][0];
#pragma unroll
    for (int kk = 0; kk < 2; ++kk) {
      short8 af[4], bfr[4];
#pragma unroll
      for (int mi = 0; mi < 4; ++mi) {
        int row = wm + mi * 16 + cc;
        int cg = kk * 4 + quad;
        af[mi] = *(const short8*)&Ac[row * 64 + (cg ^ (row & 7)) * 8];
      }
#pragma unroll
      for (int ni = 0; ni < 4; ++ni) {
        int row = wn + ni * 16 + cc;
        int cg = kk * 4 + quad;
        bfr[ni] = *(const short8*)&Bc[row * 64 + (cg ^ (row & 7)) * 8];
      }
      if (t + 2 < NT) {       // half of tile t+2's staging per phase
        if (kk == 0) { stageA2(t + 2, nxt, 0); stageB1(t + 2, nxt, 0); }
        else         { stageA2(t + 2, nxt, 2); stageB1(t + 2, nxt, 1); }
      }
      bar();                  // phase lockstep; compiler lgkmcnt covers ds deps
      __builtin_amdgcn_s_setprio(1);
#pragma unroll
      for (int mi = 0; mi < 4; ++mi)
#pragma unroll
        for (int ni = 0; ni < 4; ++ni)
          acc[mi][ni] = mfma16(af[mi], bfr[ni], acc[mi][ni]);
      __builtin_amdgcn_s_setprio(0);
      if (kk == 0) bar();
    }
    if (t < NT - 1) {         // tile boundary: make buf[(t+1)%3] readable
      if (t + 2 < NT) vwait<6>(); else vwait<0>();
      bar();
    }
    cur = (cur == 2) ? 0 : cur + 1;
    nxt = (nxt == 2) ? 0 : nxt + 1;
  }

  // Epilogue. C/D layout: col n = lane&15, row m = quad*4 + reg.
  if (mode <= 1) {
    u16* O = (u16*)Out;
    float postscale = (mode == 0) ? 0.18033688011112042f : 1.0f; // 1/8*log2e
#pragma unroll
    for (int ni = 0; ni < 4; ++ni) {
      int n = n0 + wn + ni * 16 + cc;
      int h = n >> 6, d = n & 63;
      float inv = __expf(-(float)(d & 62) * (9.210340372f / 64.0f)); // theta^{-2i/64}
      float sign = (d & 1) ? 1.0f : -1.0f;
#pragma unroll
      for (int mi = 0; mi < 4; ++mi) {
        int mB = m0 + wm + mi * 16 + quad * 4;
#pragma unroll
        for (int r = 0; r < 4; ++r) {
          int m = mB + r;
          int b = m >> 11, s = m & (Sv - 1);
          float val = acc[mi][ni][r];
          float part = __shfl_xor(val, 1);  // paired even/odd feature
          float sn, cs;
          __sincosf((float)s * inv, &sn, &cs);
          float outv = (val * cs + sign * part * sn) * postscale;
          O[((size_t)(b * Hv + h) * Sv + s) * DKv + d] = f2bf(outv);
        }
      }
    }
  } else if (mode == 2) {
    u16* O = (u16*)Out;
#pragma unroll
    for (int ni = 0; ni < 4; ++ni) {
      int n = n0 + wn + ni * 16 + cc;
      int h = n >> 6, d = n & 63;
#pragma unroll
      for (int mi = 0; mi < 4; ++mi) {
        int mB = m0 + wm + mi * 16 + quad * 4;
        int b = mB >> 11, s = mB & (Sv - 1);
        u16x4 o4 = { f2bf(acc[mi][ni][0]), f2bf(acc[mi][ni][1]),
                     f2bf(acc[mi][ni][2]), f2bf(acc[mi][ni][3]) };
        *(u16x4*)&O[((size_t)(b * Hv + h) * DKv + d) * Sv + s] = o4;
      }
    }
  } else {
    float* O = (float*)Out;
#pragma unroll
    for (int ni = 0; ni < 4; ++ni) {
      int n = n0 + wn + ni * 16 + cc;
#pragma unroll
      for (int mi = 0; mi < 4; ++mi) {
        int mB = m0 + wm + mi * 16 + quad * 4;
#pragma unroll
        for (int r = 0; r < 4; ++r)
          O[(size_t)(mB + r) * Dv + n] = acc[mi][ni][r];
      }
    }
  }
}

// ---------------------------------------------------------------------------
// Flash attention v6 (proven 91 us) — kept verbatim.
// S^T via A=K,B=Q (C col=q=c32); l via ones-B MFMA on the exchanged pu frag;
// K/V double-buffered, 33 KB LDS, __launch_bounds__(256,2).
// Qp,Kp: [bh][s][64] bf16 (Q pre-scaled by 0.125*log2e). Vt: [bh][64][s] bf16.
__global__ __launch_bounds__(256, 2) void attn(
    const u16* __restrict__ Qp, const u16* __restrict__ Kp,
    const u16* __restrict__ Vt, u16* __restrict__ ctx) {
  __shared__ u16 Ks[2][64 * 64];   // [buf][key][d], chunk-swizzled
  __shared__ u16 Vs[2][64 * 64];   // [buf][d][key], chunk-swizzled
  int tid = threadIdx.x;
  int lane = tid & 63, wid = tid >> 6;
  int hi = lane >> 5, c32 = lane & 31;
  int sz = (c32 & 7) ^ ((c32 >> 3) & 3);
  int bh = blockIdx.y;
  int q0 = blockIdx.x * 256 + wid * 64;
  const u16* Qh = Qp + (size_t)bh * Sv * DKv;
  const u16* Kh = Kp + (size_t)bh * Sv * DKv;
  const u16* Vh = Vt + (size_t)bh * Sv * DKv;

  const short8 ones = { (short)0x3F80, (short)0x3F80, (short)0x3F80, (short)0x3F80,
                        (short)0x3F80, (short)0x3F80, (short)0x3F80, (short)0x3F80 };

  // Q B-frags in registers: B[n=q=c32][k = dk*16 + hi*8 + j]
  short8 qf[2][4];
#pragma unroll
  for (int qs = 0; qs < 2; ++qs)
#pragma unroll
    for (int dk = 0; dk < 4; ++dk)
      qf[qs][dk] = *(const short8*)&Qh[(size_t)(q0 + qs * 32 + c32) * DKv + dk * 16 + hi * 8];

  f32x16 o[2][2];   // O[q][d] accum, C-layout: col=d=c32, row=q=(r&3)+8*(r>>2)+4*hi
  f32x16 ol[2];     // l accum (ones-MFMA row sums of bf16 P) — reg r matches o reg r
#pragma unroll
  for (int qs = 0; qs < 2; ++qs) {
#pragma unroll
    for (int dt = 0; dt < 2; ++dt)
#pragma unroll
      for (int r = 0; r < 16; ++r) o[qs][dt][r] = 0.f;
#pragma unroll
    for (int r = 0; r < 16; ++r) ol[qs][r] = 0.f;
  }

  // prefetch tile 0 into buf 0
#pragma unroll
  for (int p = 0; p < 2; ++p) {
    int slot = p * 256 + tid;
    int row = slot >> 3, cl = slot & 7;
    int cg = cl ^ ((row & 7) ^ ((row >> 3) & 3));
    gl_lds16(Kh + (size_t)row * DKv + cg * 8, &Ks[0][slot * 8]);
    gl_lds16(Vh + (size_t)row * Sv + cg * 8, &Vs[0][slot * 8]);
  }

  for (int kt = 0; kt < Sv / 64; ++kt) {
    int cur = kt & 1;
    __syncthreads();  // drains prefetch(kt); all waves past compute(kt-1)

    if (kt + 1 < Sv / 64) {
      int s1 = (kt + 1) * 64;
#pragma unroll
      for (int p = 0; p < 2; ++p) {
        int slot = p * 256 + tid;
        int row = slot >> 3, cl = slot & 7;
        int cg = cl ^ ((row & 7) ^ ((row >> 3) & 3));
        gl_lds16(Kh + (size_t)(s1 + row) * DKv + cg * 8, &Ks[1 - cur][slot * 8]);
        gl_lds16(Vh + (size_t)row * Sv + s1 + cg * 8, &Vs[1 - cur][slot * 8]);
      }
    }

#pragma unroll
    for (int half = 0; half < 2; ++half) {   // 32-key half = key-tile rows
      // K A-frags once per half, shared by both q-halves.
      short8 kf[4];
#pragma unroll
      for (int dk = 0; dk < 4; ++dk)
        kf[dk] = *(const short8*)&Ks[cur][(half * 32 + c32) * 64 + (((dk * 2 + hi) ^ sz)) * 8];

      // S^T for both q-halves: A=K rows (half*32+c32), B=Q. C col = q = c32.
      f32x16 st[2];
#pragma unroll
      for (int qs = 0; qs < 2; ++qs) {
#pragma unroll
        for (int r = 0; r < 16; ++r) st[qs][r] = 0.f;
#pragma unroll
        for (int dk = 0; dk < 4; ++dk)
          st[qs] = mfma32(kf[dk], qf[qs][dk], st[qs]);
      }

      // Two PV k-steps (16 keys each); vf loaded once, shared by both qs.
#pragma unroll
      for (int pp = 0; pp < 2; ++pp) {
        int pk = half * 2 + pp;
        short8 vf[2];
#pragma unroll
        for (int dt = 0; dt < 2; ++dt)
          vf[dt] = *(const short8*)&Vs[cur][(dt * 32 + c32) * 64 + (((pk * 2 + hi) ^ sz)) * 8];
#pragma unroll
        for (int qs = 0; qs < 2; ++qs) {
          float e0 = __builtin_amdgcn_exp2f(st[qs][8 * pp + 0]);
          float e1 = __builtin_amdgcn_exp2f(st[qs][8 * pp + 1]);
          float e2 = __builtin_amdgcn_exp2f(st[qs][8 * pp + 2]);
          float e3 = __builtin_amdgcn_exp2f(st[qs][8 * pp + 3]);
          float e4 = __builtin_amdgcn_exp2f(st[qs][8 * pp + 4]);
          float e5 = __builtin_amdgcn_exp2f(st[qs][8 * pp + 5]);
          float e6 = __builtin_amdgcn_exp2f(st[qs][8 * pp + 6]);
          float e7 = __builtin_amdgcn_exp2f(st[qs][8 * pp + 7]);
          uint32_t plo0 = __builtin_amdgcn_perm(__float_as_uint(e1), __float_as_uint(e0), 0x07060302u);
          uint32_t plo1 = __builtin_amdgcn_perm(__float_as_uint(e3), __float_as_uint(e2), 0x07060302u);
          uint32_t phi0 = __builtin_amdgcn_perm(__float_as_uint(e5), __float_as_uint(e4), 0x07060302u);
          uint32_t phi1 = __builtin_amdgcn_perm(__float_as_uint(e7), __float_as_uint(e6), 0x07060302u);
          uint32_t s0 = hi ? plo0 : phi0;   // pack pair sent to partner lane
          uint32_t s1 = hi ? plo1 : phi1;
          uint32_t r0 = (uint32_t)__shfl_xor((int)s0, 32);
          uint32_t r1 = (uint32_t)__shfl_xor((int)s1, 32);
          union { uint32_t u[4]; short8 s8; } pu;
          pu.u[0] = hi ? r0 : plo0;   // frag elems 0..3: data from h'=0 lane
          pu.u[1] = hi ? r1 : plo1;
          pu.u[2] = hi ? phi0 : r0;   // frag elems 4..7: data from h'=1 lane
          pu.u[3] = hi ? phi1 : r1;
          ol[qs] = mfma32(pu.s8, ones, ol[qs]);
          o[qs][0] = mfma32(pu.s8, vf[0], o[qs][0]);
          o[qs][1] = mfma32(pu.s8, vf[1], o[qs][1]);
        }
      }
    }
  }

  // normalize + write ctx[b][s=q][h*64+d]. ol reg r is the l of o reg r's row.
  int b = bh >> 4, h = bh & 15;
#pragma unroll
  for (int qs = 0; qs < 2; ++qs)
#pragma unroll
    for (int r = 0; r < 16; ++r) {
      int q = q0 + qs * 32 + (r & 3) + 8 * (r >> 2) + 4 * hi;
      float linv = 1.0f / ol[qs][r];
#pragma unroll
      for (int dt = 0; dt < 2; ++dt) {
        int d = h * DKv + dt * 32 + c32;
        ctx[((size_t)b * Sv + q) * Dv + d] = f2bf(o[qs][dt][r] * linv);
      }
    }
}

// ---------------------------------------------------------------------------
extern "C" void kernel_launch(void* const* d_in, const int* in_sizes, int n_in,
                              void* d_out, int out_size, void* d_ws, size_t ws_size,
                              hipStream_t stream) {
  (void)in_sizes; (void)n_in; (void)out_size; (void)ws_size;
  const float* q  = (const float*)d_in[0];
  const float* k  = (const float*)d_in[1];
  const float* v  = (const float*)d_in[2];
  const float* Wq = (const float*)d_in[3];
  const float* Wk = (const float*)d_in[4];
  const float* Wv = (const float*)d_in[5];
  const float* Wo = (const float*)d_in[6];

  char* ws = (char*)d_ws;
  size_t off = 0;
  const size_t big = (size_t)BSv * Dv * sizeof(u16);   // 16 MiB
  const size_t wsz = (size_t)Dv * Dv * sizeof(u16);    // 2 MiB
  u16* Wqt = (u16*)(ws + off); off += wsz;
  u16* Wkt = (u16*)(ws + off); off += wsz;
  u16* Wvt = (u16*)(ws + off); off += wsz;
  u16* Wot = (u16*)(ws + off); off += wsz;
  u16* Qp  = (u16*)(ws + off); off += big;
  u16* Kp  = (u16*)(ws + off); off += big;
  u16* Vtr = (u16*)(ws + off); off += big;
  u16* ctx = (u16*)(ws + off); off += big;

  conv_wt<<<dim3(Dv / 64, Dv / 64, 4), 256, 0, stream>>>(Wq, Wk, Wv, Wo, Wqt, Wkt, Wvt, Wot);
  // fused conv+projection: reads fp32 q/k/v directly, mode = z
  gemm_qkv<<<dim3(BSv / 128, Dv / 128, 3), 256, 0, stream>>>(
      q, k, v, Wqt, Wkt, Wvt, Qp, Kp, Vtr);
  attn<<<dim3(Sv / 256, Bv * Hv), 256, 0, stream>>>(Qp, Kp, Vtr, ctx);
  gemm_bt<<<dim3(256, 1, 1), 512, 0, stream>>>(
      ctx, ctx, ctx, Wot, Wot, Wot, d_out, d_out, d_out, 3);
}